// Round 2
// baseline (215.761 us; speedup 1.0000x reference)
//
#include <hip/hip_runtime.h>
#include <math.h>

#define NTHREADS 256
#define M_S 50      // samples on ellipse
#define N_PTS 2048  // targets per view

__global__ __launch_bounds__(NTHREADS) void chamfer_ellipse_kernel(
    const float* __restrict__ u,     // (1,6): r0,r1,r2, ax,ay,az
    const float* __restrict__ rot,   // (V,3,3)
    const float* __restrict__ tgt,   // (V,N,2)
    float* __restrict__ out)         // (V,)
{
    const int v    = blockIdx.x;
    const int tid  = threadIdx.x;
    const int lane = tid & 63;
    const int wid  = tid >> 6;

    __shared__ float4 samp[M_S];          // (-2sx, -2sy, sx^2+sy^2, 0)
    __shared__ float  wave_smin[4][M_S];
    __shared__ float  wave_ysum[4];

    // ---- issue the 8-targets-per-thread global loads early (latency hide) ----
    const float4* tp = reinterpret_cast<const float4*>(tgt + (size_t)v * (N_PTS * 2));
    float4 t0 = tp[tid];
    float4 t1 = tp[tid + 256];
    float4 t2 = tp[tid + 512];
    float4 t3 = tp[tid + 768];

    // ---- per-view setup, redundantly in threads 0..49 ----
    if (tid < M_S) {
        float r0 = u[0], r1 = u[1], r2 = u[2];
        float ax = u[3], ay = u[4], az = u[5];
        float l0 = 1.0f / (r0 * r0), l1 = 1.0f / (r1 * r1), l2 = 1.0f / (r2 * r2);
        float cx = cosf(ax), sx = sinf(ax);
        float cy = cosf(ay), sy = sinf(ay);
        float cz = cosf(az), sz = sinf(az);
        // Q = Rz @ Ry @ Rx
        float q00 = cz * cy, q01 = cz * sy * sx - sz * cx, q02 = cz * sy * cx + sz * sx;
        float q10 = sz * cy, q11 = sz * sy * sx + cz * cx, q12 = sz * sy * cx - cz * sx;
        float q20 = -sy,     q21 = cy * sx,                q22 = cy * cx;
        // A = Q diag(l) Q^T (symmetric)
        float A00 = q00 * q00 * l0 + q01 * q01 * l1 + q02 * q02 * l2;
        float A01 = q00 * q10 * l0 + q01 * q11 * l1 + q02 * q12 * l2;
        float A02 = q00 * q20 * l0 + q01 * q21 * l1 + q02 * q22 * l2;
        float A11 = q10 * q10 * l0 + q11 * q11 * l1 + q12 * q12 * l2;
        float A12 = q10 * q20 * l0 + q11 * q21 * l1 + q12 * q22 * l2;
        float A22 = q20 * q20 * l0 + q21 * q21 * l1 + q22 * q22 * l2;
        // R (per view)
        const float* Rv = rot + v * 9;
        float R00 = Rv[0], R01 = Rv[1], R02 = Rv[2];
        float R10 = Rv[3], R11 = Rv[4], R12 = Rv[5];
        float R20 = Rv[6], R21 = Rv[7], R22 = Rv[8];
        // T = R A  (A symmetric)
        float T00 = R00 * A00 + R01 * A01 + R02 * A02;
        float T01 = R00 * A01 + R01 * A11 + R02 * A12;
        float T02 = R00 * A02 + R01 * A12 + R02 * A22;
        float T10 = R10 * A00 + R11 * A01 + R12 * A02;
        float T11 = R10 * A01 + R11 * A11 + R12 * A12;
        float T12 = R10 * A02 + R11 * A12 + R12 * A22;
        float T20 = R20 * A00 + R21 * A01 + R22 * A02;
        float T21 = R20 * A01 + R21 * A11 + R22 * A12;
        float T22 = R20 * A02 + R21 * A12 + R22 * A22;
        // M = T R^T (symmetric)
        float Ma = T00 * R00 + T01 * R01 + T02 * R02;
        float Mb = T00 * R10 + T01 * R11 + T02 * R12;
        float Mc = T00 * R20 + T01 * R21 + T02 * R22;
        float Md = T10 * R00 + T11 * R01 + T12 * R02;
        float Me = T10 * R10 + T11 * R11 + T12 * R12;
        float Mf = T10 * R20 + T11 * R21 + T12 * R22;
        float Mg = T20 * R00 + T21 * R01 + T22 * R02;
        float Mh = T20 * R10 + T21 * R11 + T22 * R12;
        float Mi = T20 * R20 + T21 * R21 + T22 * R22;
        // top-left 2x2 of M^-1 via adjugate
        float c00 = Me * Mi - Mf * Mh;
        float c01 = Mc * Mh - Mb * Mi;
        float c10 = Mf * Mg - Md * Mi;
        float c11 = Ma * Mi - Mc * Mg;
        float det = Ma * c00 + Mb * c10 + Mc * (Md * Mh - Me * Mg);
        float idet = 1.0f / det;
        float p = c00 * idet, q = c01 * idet, r = c10 * idet, s = c11 * idet;
        // C = inv(B2)
        float idet2 = 1.0f / (p * s - q * r);
        float C00 = s * idet2, C10 = -r * idet2, C11 = p * idet2;
        // lower Cholesky of C; U = L^T
        float L00 = sqrtf(C00);
        float L10 = C10 / L00;
        float L11 = sqrtf(C11 - L10 * L10);
        // U^-1 (upper tri): [[1/L00, -L10/(L00*L11)],[0, 1/L11]]
        float iu00 = 1.0f / L00;
        float iu11 = 1.0f / L11;
        float iu01 = -L10 * iu00 * iu11;
        // sample point m = tid
        float t  = 6.283185307179586f * ((float)tid * (1.0f / 49.0f));
        float ct = cosf(t), st = sinf(t);
        float sxp = iu00 * ct + iu01 * st;
        float syp = iu11 * st;
        samp[tid] = make_float4(-2.0f * sxp, -2.0f * syp, sxp * sxp + syp * syp, 0.0f);
    }
    __syncthreads();

    // ---- register-resident targets ----
    float tx[8] = {t0.x, t0.z, t1.x, t1.z, t2.x, t2.z, t3.x, t3.z};
    float ty[8] = {t0.y, t0.w, t1.y, t1.w, t2.y, t2.w, t3.y, t3.w};
    float yy[8], ymin[8];
#pragma unroll
    for (int j = 0; j < 8; ++j) {
        yy[j]   = tx[j] * tx[j] + ty[j] * ty[j];
        ymin[j] = INFINITY;
    }
    float smin[M_S];
#pragma unroll
    for (int s2 = 0; s2 < M_S; ++s2) smin[s2] = INFINITY;

    // ---- main chamfer loop: 50 samples x 8 targets, d2 = xx + yy - 2*xy ----
#pragma unroll
    for (int s2 = 0; s2 < M_S; ++s2) {
        float4 sp = samp[s2];
        float  sm = smin[s2];
#pragma unroll
        for (int j = 0; j < 8; ++j) {
            float d2 = fmaf(sp.x, tx[j], fmaf(sp.y, ty[j], sp.z + yy[j]));
            ymin[j]  = fminf(ymin[j], d2);
            sm       = fminf(sm, d2);
        }
        smin[s2] = sm;
    }

    // ---- cham_y: sum of per-target mins ----
    float ysum = 0.0f;
#pragma unroll
    for (int j = 0; j < 8; ++j) ysum += ymin[j];
#pragma unroll
    for (int off = 32; off > 0; off >>= 1) ysum += __shfl_xor(ysum, off);
    if (lane == 0) wave_ysum[wid] = ysum;

    // ---- cham_x: per-sample block-min ----
#pragma unroll
    for (int s2 = 0; s2 < M_S; ++s2) {
        float m = smin[s2];
        m = fminf(m, __shfl_xor(m, 32));
        m = fminf(m, __shfl_xor(m, 16));
        m = fminf(m, __shfl_xor(m, 8));
        m = fminf(m, __shfl_xor(m, 4));
        m = fminf(m, __shfl_xor(m, 2));
        m = fminf(m, __shfl_xor(m, 1));
        if (lane == 0) wave_smin[wid][s2] = m;
    }
    __syncthreads();

    if (wid == 0) {
        float val = 0.0f;
        if (lane < M_S) {
            float m = wave_smin[0][lane];
            m = fminf(m, wave_smin[1][lane]);
            m = fminf(m, wave_smin[2][lane]);
            m = fminf(m, wave_smin[3][lane]);
            val = m;
        }
#pragma unroll
        for (int off = 32; off > 0; off >>= 1) val += __shfl_xor(val, off);
        if (lane == 0) {
            float ysum_tot = wave_ysum[0] + wave_ysum[1] + wave_ysum[2] + wave_ysum[3];
            out[v] = val * (1.0f / (float)M_S) + ysum_tot * (1.0f / (float)N_PTS);
        }
    }
}

extern "C" void kernel_launch(void* const* d_in, const int* in_sizes, int n_in,
                              void* d_out, int out_size, void* d_ws, size_t ws_size,
                              hipStream_t stream) {
    const float* u   = (const float*)d_in[0];
    const float* rot = (const float*)d_in[1];
    const float* tgt = (const float*)d_in[2];
    float* out = (float*)d_out;

    const int V = in_sizes[1] / 9;  // 2048
    chamfer_ellipse_kernel<<<V, NTHREADS, 0, stream>>>(u, rot, tgt, out);
}

// Round 3
// 116.695 us; speedup vs baseline: 1.8489x; 1.8489x over previous
//
#include <hip/hip_runtime.h>
#include <math.h>

#define NTHREADS 256
#define M_S 50      // samples on ellipse
#define N_PTS 2048  // targets per view
#define GROUP 10    // samples per register group (5 groups x 10 = 50)

__global__ __launch_bounds__(NTHREADS, 4) void chamfer_ellipse_kernel(
    const float* __restrict__ u,     // (1,6): r0,r1,r2, ax,ay,az
    const float* __restrict__ rot,   // (V,3,3)
    const float* __restrict__ tgt,   // (V,N,2)
    float* __restrict__ out)         // (V,)
{
    const int v    = blockIdx.x;
    const int tid  = threadIdx.x;
    const int lane = tid & 63;
    const int wid  = tid >> 6;

    __shared__ float4 samp[M_S];          // (-2sx, -2sy, sx^2+sy^2, 0)
    __shared__ float  wave_smin[4][M_S];
    __shared__ float  wave_ysum[4];

    // ---- issue the 8-targets-per-thread global loads early (latency hide) ----
    const float4* tp = reinterpret_cast<const float4*>(tgt + (size_t)v * (N_PTS * 2));
    float4 t0 = tp[tid];
    float4 t1 = tp[tid + 256];
    float4 t2 = tp[tid + 512];
    float4 t3 = tp[tid + 768];

    // ---- per-view setup, redundantly in threads 0..49 ----
    if (tid < M_S) {
        float r0 = u[0], r1 = u[1], r2 = u[2];
        float ax = u[3], ay = u[4], az = u[5];
        float l0 = 1.0f / (r0 * r0), l1 = 1.0f / (r1 * r1), l2 = 1.0f / (r2 * r2);
        float cx = cosf(ax), sx = sinf(ax);
        float cy = cosf(ay), sy = sinf(ay);
        float cz = cosf(az), sz = sinf(az);
        // Q = Rz @ Ry @ Rx
        float q00 = cz * cy, q01 = cz * sy * sx - sz * cx, q02 = cz * sy * cx + sz * sx;
        float q10 = sz * cy, q11 = sz * sy * sx + cz * cx, q12 = sz * sy * cx - cz * sx;
        float q20 = -sy,     q21 = cy * sx,                q22 = cy * cx;
        // A = Q diag(l) Q^T (symmetric)
        float A00 = q00 * q00 * l0 + q01 * q01 * l1 + q02 * q02 * l2;
        float A01 = q00 * q10 * l0 + q01 * q11 * l1 + q02 * q12 * l2;
        float A02 = q00 * q20 * l0 + q01 * q21 * l1 + q02 * q22 * l2;
        float A11 = q10 * q10 * l0 + q11 * q11 * l1 + q12 * q12 * l2;
        float A12 = q10 * q20 * l0 + q11 * q21 * l1 + q12 * q22 * l2;
        float A22 = q20 * q20 * l0 + q21 * q21 * l1 + q22 * q22 * l2;
        // R (per view)
        const float* Rv = rot + v * 9;
        float R00 = Rv[0], R01 = Rv[1], R02 = Rv[2];
        float R10 = Rv[3], R11 = Rv[4], R12 = Rv[5];
        float R20 = Rv[6], R21 = Rv[7], R22 = Rv[8];
        // T = R A  (A symmetric)
        float T00 = R00 * A00 + R01 * A01 + R02 * A02;
        float T01 = R00 * A01 + R01 * A11 + R02 * A12;
        float T02 = R00 * A02 + R01 * A12 + R02 * A22;
        float T10 = R10 * A00 + R11 * A01 + R12 * A02;
        float T11 = R10 * A01 + R11 * A11 + R12 * A12;
        float T12 = R10 * A02 + R11 * A12 + R12 * A22;
        float T20 = R20 * A00 + R21 * A01 + R22 * A02;
        float T21 = R20 * A01 + R21 * A11 + R22 * A12;
        float T22 = R20 * A02 + R21 * A12 + R22 * A22;
        // M = T R^T (symmetric)
        float Ma = T00 * R00 + T01 * R01 + T02 * R02;
        float Mb = T00 * R10 + T01 * R11 + T02 * R12;
        float Mc = T00 * R20 + T01 * R21 + T02 * R22;
        float Md = T10 * R00 + T11 * R01 + T12 * R02;
        float Me = T10 * R10 + T11 * R11 + T12 * R12;
        float Mf = T10 * R20 + T11 * R21 + T12 * R22;
        float Mg = T20 * R00 + T21 * R01 + T22 * R02;
        float Mh = T20 * R10 + T21 * R11 + T22 * R12;
        float Mi = T20 * R20 + T21 * R21 + T22 * R22;
        // top-left 2x2 of M^-1 via adjugate
        float c00 = Me * Mi - Mf * Mh;
        float c01 = Mc * Mh - Mb * Mi;
        float c10 = Mf * Mg - Md * Mi;
        float c11 = Ma * Mi - Mc * Mg;
        float det = Ma * c00 + Mb * c10 + Mc * (Md * Mh - Me * Mg);
        float idet = 1.0f / det;
        float p = c00 * idet, q = c01 * idet, r = c10 * idet, s = c11 * idet;
        // C = inv(B2)
        float idet2 = 1.0f / (p * s - q * r);
        float C00 = s * idet2, C10 = -r * idet2, C11 = p * idet2;
        // lower Cholesky of C; U = L^T
        float L00 = sqrtf(C00);
        float L10 = C10 / L00;
        float L11 = sqrtf(C11 - L10 * L10);
        // U^-1 (upper tri): [[1/L00, -L10/(L00*L11)],[0, 1/L11]]
        float iu00 = 1.0f / L00;
        float iu11 = 1.0f / L11;
        float iu01 = -L10 * iu00 * iu11;
        // sample point m = tid
        float t  = 6.283185307179586f * ((float)tid * (1.0f / 49.0f));
        float ct = cosf(t), st = sinf(t);
        float sxp = iu00 * ct + iu01 * st;
        float syp = iu11 * st;
        samp[tid] = make_float4(-2.0f * sxp, -2.0f * syp, sxp * sxp + syp * syp, 0.0f);
    }
    __syncthreads();

    // ---- register-resident targets ----
    float tx[8] = {t0.x, t0.z, t1.x, t1.z, t2.x, t2.z, t3.x, t3.z};
    float ty[8] = {t0.y, t0.w, t1.y, t1.w, t2.y, t2.w, t3.y, t3.w};
    float yy[8], ymin[8];
#pragma unroll
    for (int j = 0; j < 8; ++j) {
        yy[j]   = tx[j] * tx[j] + ty[j] * ty[j];
        ymin[j] = INFINITY;
    }

    // ---- main chamfer loop: 5 runtime groups of 10 samples (keeps VGPR low) ----
    for (int g = 0; g < 5; ++g) {
        // batch the 10 LDS reads so their latency pipelines
        float4 sp[GROUP];
#pragma unroll
        for (int k = 0; k < GROUP; ++k) sp[k] = samp[g * GROUP + k];

        float sminG[GROUP];
#pragma unroll
        for (int k = 0; k < GROUP; ++k) {
            float d[8];
#pragma unroll
            for (int j = 0; j < 8; ++j)
                d[j] = fmaf(sp[k].x, tx[j], fmaf(sp[k].y, ty[j], sp[k].z + yy[j]));
#pragma unroll
            for (int j = 0; j < 8; ++j)
                ymin[j] = fminf(ymin[j], d[j]);
            // tree-min (min3-fusable, short dependency chain)
            float m01 = fminf(d[0], d[1]), m23 = fminf(d[2], d[3]);
            float m45 = fminf(d[4], d[5]), m67 = fminf(d[6], d[7]);
            sminG[k] = fminf(fminf(m01, m23), fminf(m45, m67));
        }

        // reduce this group's sample-mins across the wave, park in LDS
#pragma unroll
        for (int k = 0; k < GROUP; ++k) {
            float m = sminG[k];
            m = fminf(m, __shfl_xor(m, 32));
            m = fminf(m, __shfl_xor(m, 16));
            m = fminf(m, __shfl_xor(m, 8));
            m = fminf(m, __shfl_xor(m, 4));
            m = fminf(m, __shfl_xor(m, 2));
            m = fminf(m, __shfl_xor(m, 1));
            if (lane == 0) wave_smin[wid][g * GROUP + k] = m;
        }
    }

    // ---- cham_y: sum of per-target mins ----
    float ysum = 0.0f;
#pragma unroll
    for (int j = 0; j < 8; ++j) ysum += ymin[j];
#pragma unroll
    for (int off = 32; off > 0; off >>= 1) ysum += __shfl_xor(ysum, off);
    if (lane == 0) wave_ysum[wid] = ysum;
    __syncthreads();

    if (wid == 0) {
        float val = 0.0f;
        if (lane < M_S) {
            float m = wave_smin[0][lane];
            m = fminf(m, wave_smin[1][lane]);
            m = fminf(m, wave_smin[2][lane]);
            m = fminf(m, wave_smin[3][lane]);
            val = m;
        }
#pragma unroll
        for (int off = 32; off > 0; off >>= 1) val += __shfl_xor(val, off);
        if (lane == 0) {
            float ysum_tot = wave_ysum[0] + wave_ysum[1] + wave_ysum[2] + wave_ysum[3];
            out[v] = val * (1.0f / (float)M_S) + ysum_tot * (1.0f / (float)N_PTS);
        }
    }
}

extern "C" void kernel_launch(void* const* d_in, const int* in_sizes, int n_in,
                              void* d_out, int out_size, void* d_ws, size_t ws_size,
                              hipStream_t stream) {
    const float* u   = (const float*)d_in[0];
    const float* rot = (const float*)d_in[1];
    const float* tgt = (const float*)d_in[2];
    float* out = (float*)d_out;

    const int V = in_sizes[1] / 9;  // 2048
    chamfer_ellipse_kernel<<<V, NTHREADS, 0, stream>>>(u, rot, tgt, out);
}

// Round 4
// 104.823 us; speedup vs baseline: 2.0583x; 1.1133x over previous
//
#include <hip/hip_runtime.h>
#include <math.h>

#define NTHREADS 256
#define M_S 50      // samples on ellipse
#define N_PTS 2048  // targets per view

__global__ __launch_bounds__(NTHREADS, 6) void chamfer_ellipse_kernel(
    const float* __restrict__ u,     // (1,6): r0,r1,r2, ax,ay,az
    const float* __restrict__ rot,   // (V,3,3)
    const float* __restrict__ tgt,   // (V,N,2)
    float* __restrict__ out)         // (V,)
{
    const int v    = blockIdx.x;
    const int tid  = threadIdx.x;
    const int lane = tid & 63;
    const int wid  = tid >> 6;

    __shared__ float4 samp[M_S];       // (-2sx, -2sy, sx^2+sy^2, 0)
    __shared__ float  part[128][M_S];  // per-lane-pair sample mins (25.6 KB)
    __shared__ float  wave_ysum[4];

    // ---- issue the 8-targets-per-thread global loads early (latency hide) ----
    const float4* tp = reinterpret_cast<const float4*>(tgt + (size_t)v * (N_PTS * 2));
    float4 t0 = tp[tid];
    float4 t1 = tp[tid + 256];
    float4 t2 = tp[tid + 512];
    float4 t3 = tp[tid + 768];

    // ---- per-view setup, redundantly in threads 0..49 ----
    if (tid < M_S) {
        float r0 = u[0], r1 = u[1], r2 = u[2];
        float ax = u[3], ay = u[4], az = u[5];
        float l0 = 1.0f / (r0 * r0), l1 = 1.0f / (r1 * r1), l2 = 1.0f / (r2 * r2);
        float cx = cosf(ax), sx = sinf(ax);
        float cy = cosf(ay), sy = sinf(ay);
        float cz = cosf(az), sz = sinf(az);
        // Q = Rz @ Ry @ Rx
        float q00 = cz * cy, q01 = cz * sy * sx - sz * cx, q02 = cz * sy * cx + sz * sx;
        float q10 = sz * cy, q11 = sz * sy * sx + cz * cx, q12 = sz * sy * cx - cz * sx;
        float q20 = -sy,     q21 = cy * sx,                q22 = cy * cx;
        // A = Q diag(l) Q^T (symmetric)
        float A00 = q00 * q00 * l0 + q01 * q01 * l1 + q02 * q02 * l2;
        float A01 = q00 * q10 * l0 + q01 * q11 * l1 + q02 * q12 * l2;
        float A02 = q00 * q20 * l0 + q01 * q21 * l1 + q02 * q22 * l2;
        float A11 = q10 * q10 * l0 + q11 * q11 * l1 + q12 * q12 * l2;
        float A12 = q10 * q20 * l0 + q11 * q21 * l1 + q12 * q22 * l2;
        float A22 = q20 * q20 * l0 + q21 * q21 * l1 + q22 * q22 * l2;
        // R (per view)
        const float* Rv = rot + v * 9;
        float R00 = Rv[0], R01 = Rv[1], R02 = Rv[2];
        float R10 = Rv[3], R11 = Rv[4], R12 = Rv[5];
        float R20 = Rv[6], R21 = Rv[7], R22 = Rv[8];
        // T = R A  (A symmetric)
        float T00 = R00 * A00 + R01 * A01 + R02 * A02;
        float T01 = R00 * A01 + R01 * A11 + R02 * A12;
        float T02 = R00 * A02 + R01 * A12 + R02 * A22;
        float T10 = R10 * A00 + R11 * A01 + R12 * A02;
        float T11 = R10 * A01 + R11 * A11 + R12 * A12;
        float T12 = R10 * A02 + R11 * A12 + R12 * A22;
        float T20 = R20 * A00 + R21 * A01 + R22 * A02;
        float T21 = R20 * A01 + R21 * A11 + R22 * A12;
        float T22 = R20 * A02 + R21 * A12 + R22 * A22;
        // M = T R^T (symmetric)
        float Ma = T00 * R00 + T01 * R01 + T02 * R02;
        float Mb = T00 * R10 + T01 * R11 + T02 * R12;
        float Mc = T00 * R20 + T01 * R21 + T02 * R22;
        float Md = T10 * R00 + T11 * R01 + T12 * R02;
        float Me = T10 * R10 + T11 * R11 + T12 * R12;
        float Mf = T10 * R20 + T11 * R21 + T12 * R22;
        float Mg = T20 * R00 + T21 * R01 + T22 * R02;
        float Mh = T20 * R10 + T21 * R11 + T22 * R12;
        float Mi = T20 * R20 + T21 * R21 + T22 * R22;
        // top-left 2x2 of M^-1 via adjugate
        float c00 = Me * Mi - Mf * Mh;
        float c01 = Mc * Mh - Mb * Mi;
        float c10 = Mf * Mg - Md * Mi;
        float c11 = Ma * Mi - Mc * Mg;
        float det = Ma * c00 + Mb * c10 + Mc * (Md * Mh - Me * Mg);
        float idet = 1.0f / det;
        float p = c00 * idet, q = c01 * idet, r = c10 * idet, s = c11 * idet;
        // C = inv(B2)
        float idet2 = 1.0f / (p * s - q * r);
        float C00 = s * idet2, C10 = -r * idet2, C11 = p * idet2;
        // lower Cholesky of C; U = L^T
        float L00 = sqrtf(C00);
        float L10 = C10 / L00;
        float L11 = sqrtf(C11 - L10 * L10);
        // U^-1 (upper tri): [[1/L00, -L10/(L00*L11)],[0, 1/L11]]
        float iu00 = 1.0f / L00;
        float iu11 = 1.0f / L11;
        float iu01 = -L10 * iu00 * iu11;
        // sample point m = tid
        float t  = 6.283185307179586f * ((float)tid * (1.0f / 49.0f));
        float ct = cosf(t), st = sinf(t);
        float sxp = iu00 * ct + iu01 * st;
        float syp = iu11 * st;
        samp[tid] = make_float4(-2.0f * sxp, -2.0f * syp, sxp * sxp + syp * syp, 0.0f);
    }
    __syncthreads();

    // ---- register-resident targets ----
    float tx[8] = {t0.x, t0.z, t1.x, t1.z, t2.x, t2.z, t3.x, t3.z};
    float ty[8] = {t0.y, t0.w, t1.y, t1.w, t2.y, t2.w, t3.y, t3.w};
    float yy[8], ymin[8];
#pragma unroll
    for (int j = 0; j < 8; ++j) {
        yy[j]   = tx[j] * tx[j] + ty[j] * ty[j];
        ymin[j] = INFINITY;
    }

    // ---- main chamfer loop: 25 pairs of samples, runtime loop (low VGPR) ----
    const int prow = wid * 32 + (lane >> 1);  // 0..127, one row per lane pair
    for (int g = 0; g < 25; ++g) {
        float4 sp0 = samp[2 * g];
        float4 sp1 = samp[2 * g + 1];
        float d0[8], d1[8];
#pragma unroll
        for (int j = 0; j < 8; ++j)
            d0[j] = fmaf(sp0.x, tx[j], fmaf(sp0.y, ty[j], sp0.z + yy[j]));
#pragma unroll
        for (int j = 0; j < 8; ++j)
            d1[j] = fmaf(sp1.x, tx[j], fmaf(sp1.y, ty[j], sp1.z + yy[j]));
        // per-target running min over both samples (min3-fusable)
#pragma unroll
        for (int j = 0; j < 8; ++j)
            ymin[j] = fminf(fminf(ymin[j], d0[j]), d1[j]);
        // per-sample tree mins over the 8 targets (min3-fusable)
        float a0 = fminf(fminf(d0[0], d0[1]), d0[2]);
        float b0 = fminf(fminf(d0[3], d0[4]), d0[5]);
        float c0 = fminf(d0[6], d0[7]);
        float m0 = fminf(fminf(a0, b0), c0);
        float a1 = fminf(fminf(d1[0], d1[1]), d1[2]);
        float b1 = fminf(fminf(d1[3], d1[4]), d1[5]);
        float c1 = fminf(d1[6], d1[7]);
        float m1 = fminf(fminf(a1, b1), c1);
        // one xor-1 shuffle (DPP quad-perm, cheap), even lane parks partials
        m0 = fminf(m0, __shfl_xor(m0, 1));
        m1 = fminf(m1, __shfl_xor(m1, 1));
        if ((lane & 1) == 0) {
            part[prow][2 * g]     = m0;   // adjacent -> ds_write_b64
            part[prow][2 * g + 1] = m1;
        }
    }

    // ---- cham_y: sum of per-target mins ----
    float ysum = 0.0f;
#pragma unroll
    for (int j = 0; j < 8; ++j) ysum += ymin[j];
#pragma unroll
    for (int off = 32; off > 0; off >>= 1) ysum += __shfl_xor(ysum, off);
    if (lane == 0) wave_ysum[wid] = ysum;
    __syncthreads();

    // ---- cham_x: reduce 128 partials per sample (threads 0..49), then sum ----
    if (wid == 0) {
        float val = 0.0f;
        if (lane < M_S) {
            float m = INFINITY;
#pragma unroll 4
            for (int j = 0; j < 128; ++j)
                m = fminf(m, part[j][lane]);
            val = m;
        }
#pragma unroll
        for (int off = 32; off > 0; off >>= 1) val += __shfl_xor(val, off);
        if (lane == 0) {
            float ysum_tot = wave_ysum[0] + wave_ysum[1] + wave_ysum[2] + wave_ysum[3];
            out[v] = val * (1.0f / (float)M_S) + ysum_tot * (1.0f / (float)N_PTS);
        }
    }
}

extern "C" void kernel_launch(void* const* d_in, const int* in_sizes, int n_in,
                              void* d_out, int out_size, void* d_ws, size_t ws_size,
                              hipStream_t stream) {
    const float* u   = (const float*)d_in[0];
    const float* rot = (const float*)d_in[1];
    const float* tgt = (const float*)d_in[2];
    float* out = (float*)d_out;

    const int V = in_sizes[1] / 9;  // 2048
    chamfer_ellipse_kernel<<<V, NTHREADS, 0, stream>>>(u, rot, tgt, out);
}

// Round 6
// 101.035 us; speedup vs baseline: 2.1355x; 1.0375x over previous
//
#include <hip/hip_runtime.h>
#include <math.h>

#define NTHREADS 256
#define M_S 50      // samples on ellipse
#define N_PTS 2048  // targets per view
#define PROWS 64    // one partial row per quad (256 threads / 4)
#define PCOLS 52    // 50 samples padded to 52 (16B-aligned rows, bank spread)

// quad-local min via DPP quad_perm (pure VALU, no DS pipe, ~4cy latency)
__device__ __forceinline__ float qmin_x1(float x) {
    int t = __builtin_amdgcn_update_dpp(0, __float_as_int(x), 0xB1 /*[1,0,3,2]*/, 0xF, 0xF, true);
    return fminf(x, __int_as_float(t));
}
__device__ __forceinline__ float qmin_x2(float x) {
    int t = __builtin_amdgcn_update_dpp(0, __float_as_int(x), 0x4E /*[2,3,0,1]*/, 0xF, 0xF, true);
    return fminf(x, __int_as_float(t));
}

__global__ __launch_bounds__(NTHREADS, 8) void chamfer_ellipse_kernel(
    const float* __restrict__ u,     // (1,6): r0,r1,r2, ax,ay,az
    const float* __restrict__ rot,   // (V,3,3)
    const float* __restrict__ tgt,   // (V,N,2)
    float* __restrict__ out)         // (V,)
{
    const int v    = blockIdx.x;
    const int tid  = threadIdx.x;
    const int lane = tid & 63;
    const int wid  = tid >> 6;

    __shared__ float4 samp[M_S];          // (-2sx, -2sy, sx^2+sy^2, 0)
    __shared__ float  part[PROWS][PCOLS]; // per-quad sample mins (13.3 KB)
    __shared__ float  wave_ysum[4];

    // ---- issue the 8-targets-per-thread global loads early (latency hide) ----
    const float4* tp = reinterpret_cast<const float4*>(tgt + (size_t)v * (N_PTS * 2));
    float4 t0 = tp[tid];
    float4 t1 = tp[tid + 256];
    float4 t2 = tp[tid + 512];
    float4 t3 = tp[tid + 768];

    // ---- per-view setup, redundantly in threads 0..49 ----
    if (tid < M_S) {
        float r0 = u[0], r1 = u[1], r2 = u[2];
        float ax = u[3], ay = u[4], az = u[5];
        float l0 = 1.0f / (r0 * r0), l1 = 1.0f / (r1 * r1), l2 = 1.0f / (r2 * r2);
        float cx = cosf(ax), sx = sinf(ax);
        float cy = cosf(ay), sy = sinf(ay);
        float cz = cosf(az), sz = sinf(az);
        // Q = Rz @ Ry @ Rx
        float q00 = cz * cy, q01 = cz * sy * sx - sz * cx, q02 = cz * sy * cx + sz * sx;
        float q10 = sz * cy, q11 = sz * sy * sx + cz * cx, q12 = sz * sy * cx - cz * sx;
        float q20 = -sy,     q21 = cy * sx,                q22 = cy * cx;
        // A = Q diag(l) Q^T (symmetric)
        float A00 = q00 * q00 * l0 + q01 * q01 * l1 + q02 * q02 * l2;
        float A01 = q00 * q10 * l0 + q01 * q11 * l1 + q02 * q12 * l2;
        float A02 = q00 * q20 * l0 + q01 * q21 * l1 + q02 * q22 * l2;
        float A11 = q10 * q10 * l0 + q11 * q11 * l1 + q12 * q12 * l2;
        float A12 = q10 * q20 * l0 + q11 * q21 * l1 + q12 * q22 * l2;
        float A22 = q20 * q20 * l0 + q21 * q21 * l1 + q22 * q22 * l2;
        // R (per view)
        const float* Rv = rot + v * 9;
        float R00 = Rv[0], R01 = Rv[1], R02 = Rv[2];
        float R10 = Rv[3], R11 = Rv[4], R12 = Rv[5];
        float R20 = Rv[6], R21 = Rv[7], R22 = Rv[8];
        // T = R A  (A symmetric)
        float T00 = R00 * A00 + R01 * A01 + R02 * A02;
        float T01 = R00 * A01 + R01 * A11 + R02 * A12;
        float T02 = R00 * A02 + R01 * A12 + R02 * A22;
        float T10 = R10 * A00 + R11 * A01 + R12 * A02;
        float T11 = R10 * A01 + R11 * A11 + R12 * A12;
        float T12 = R10 * A02 + R11 * A12 + R12 * A22;
        float T20 = R20 * A00 + R21 * A01 + R22 * A02;
        float T21 = R20 * A01 + R21 * A11 + R22 * A12;
        float T22 = R20 * A02 + R21 * A12 + R22 * A22;
        // M = T R^T (symmetric)
        float Ma = T00 * R00 + T01 * R01 + T02 * R02;
        float Mb = T00 * R10 + T01 * R11 + T02 * R12;
        float Mc = T00 * R20 + T01 * R21 + T02 * R22;
        float Md = T10 * R00 + T11 * R01 + T12 * R02;
        float Me = T10 * R10 + T11 * R11 + T12 * R12;
        float Mf = T10 * R20 + T11 * R21 + T12 * R22;
        float Mg = T20 * R00 + T21 * R01 + T22 * R02;
        float Mh = T20 * R10 + T21 * R11 + T22 * R12;
        float Mi = T20 * R20 + T21 * R21 + T22 * R22;
        // top-left 2x2 of M^-1 via adjugate
        float c00 = Me * Mi - Mf * Mh;
        float c01 = Mc * Mh - Mb * Mi;
        float c10 = Mf * Mg - Md * Mi;
        float c11 = Ma * Mi - Mc * Mg;
        float det = Ma * c00 + Mb * c10 + Mc * (Md * Mh - Me * Mg);
        float idet = 1.0f / det;
        float p = c00 * idet, q = c01 * idet, r = c10 * idet, s = c11 * idet;
        // C = inv(B2)
        float idet2 = 1.0f / (p * s - q * r);
        float C00 = s * idet2, C10 = -r * idet2, C11 = p * idet2;
        // lower Cholesky of C; U = L^T
        float L00 = sqrtf(C00);
        float L10 = C10 / L00;
        float L11 = sqrtf(C11 - L10 * L10);
        // U^-1 (upper tri): [[1/L00, -L10/(L00*L11)],[0, 1/L11]]
        float iu00 = 1.0f / L00;
        float iu11 = 1.0f / L11;
        float iu01 = -L10 * iu00 * iu11;
        // sample point m = tid
        float t  = 6.283185307179586f * ((float)tid * (1.0f / 49.0f));
        float ct = cosf(t), st = sinf(t);
        float sxp = iu00 * ct + iu01 * st;
        float syp = iu11 * st;
        samp[tid] = make_float4(-2.0f * sxp, -2.0f * syp, sxp * sxp + syp * syp, 0.0f);
    }
    __syncthreads();

    // ---- register-resident targets ----
    float tx[8] = {t0.x, t0.z, t1.x, t1.z, t2.x, t2.z, t3.x, t3.z};
    float ty[8] = {t0.y, t0.w, t1.y, t1.w, t2.y, t2.w, t3.y, t3.w};
    float yy[8], ymin[8];
#pragma unroll
    for (int j = 0; j < 8; ++j) {
        yy[j]   = tx[j] * tx[j] + ty[j] * ty[j];
        ymin[j] = INFINITY;
    }

    // ---- main chamfer loop: 25 pairs of samples, runtime loop (low VGPR) ----
    const int  prow   = tid >> 2;            // one partial row per quad
    const bool writer = ((lane & 3) == 0);
    for (int g = 0; g < 25; ++g) {
        float4 sp0 = samp[2 * g];
        float4 sp1 = samp[2 * g + 1];
        float d0[8], d1[8];
#pragma unroll
        for (int j = 0; j < 8; ++j)
            d0[j] = fmaf(sp0.x, tx[j], fmaf(sp0.y, ty[j], sp0.z + yy[j]));
#pragma unroll
        for (int j = 0; j < 8; ++j)
            d1[j] = fmaf(sp1.x, tx[j], fmaf(sp1.y, ty[j], sp1.z + yy[j]));
        // per-target running min over both samples (min3-fusable)
#pragma unroll
        for (int j = 0; j < 8; ++j)
            ymin[j] = fminf(fminf(ymin[j], d0[j]), d1[j]);
        // per-sample tree mins over the 8 targets (min3-fusable)
        float m0 = fminf(fminf(fminf(fminf(d0[0], d0[1]), d0[2]),
                               fminf(fminf(d0[3], d0[4]), d0[5])),
                         fminf(d0[6], d0[7]));
        float m1 = fminf(fminf(fminf(fminf(d1[0], d1[1]), d1[2]),
                               fminf(fminf(d1[3], d1[4]), d1[5])),
                         fminf(d1[6], d1[7]));
        // quad reduction on the VALU pipe (DPP), lane&3==0 parks partials
        m0 = qmin_x2(qmin_x1(m0));
        m1 = qmin_x2(qmin_x1(m1));
        if (writer) {
            part[prow][2 * g]     = m0;   // adjacent -> ds_write_b64
            part[prow][2 * g + 1] = m1;
        }
    }

    // ---- cham_y: sum of per-target mins ----
    float ysum = 0.0f;
#pragma unroll
    for (int j = 0; j < 8; ++j) ysum += ymin[j];
#pragma unroll
    for (int off = 32; off > 0; off >>= 1) ysum += __shfl_xor(ysum, off);
    if (lane == 0) wave_ysum[wid] = ysum;
    __syncthreads();

    // ---- cham_x: reduce 64 quad-partials per sample (threads 0..49) ----
    if (wid == 0) {
        float val = 0.0f;
        if (lane < M_S) {
            float m = INFINITY;
#pragma unroll 8
            for (int j = 0; j < PROWS; ++j)
                m = fminf(m, part[j][lane]);
            val = m;
        }
#pragma unroll
        for (int off = 32; off > 0; off >>= 1) val += __shfl_xor(val, off);
        if (lane == 0) {
            float ysum_tot = wave_ysum[0] + wave_ysum[1] + wave_ysum[2] + wave_ysum[3];
            out[v] = val * (1.0f / (float)M_S) + ysum_tot * (1.0f / (float)N_PTS);
        }
    }
}

extern "C" void kernel_launch(void* const* d_in, const int* in_sizes, int n_in,
                              void* d_out, int out_size, void* d_ws, size_t ws_size,
                              hipStream_t stream) {
    const float* u   = (const float*)d_in[0];
    const float* rot = (const float*)d_in[1];
    const float* tgt = (const float*)d_in[2];
    float* out = (float*)d_out;

    const int V = in_sizes[1] / 9;  // 2048
    chamfer_ellipse_kernel<<<V, NTHREADS, 0, stream>>>(u, rot, tgt, out);
}